// Round 3
// baseline (889.225 us; speedup 1.0000x reference)
//
#include <hip/hip_runtime.h>
#include <hip/hip_bf16.h>

#define NNODES 50000
#define NEDGES 1600000
#define NF 128
#define NC 40
#define NLAYERS 3
#define NPB 64                      // nodes per bucket
#define NBUCKETS ((NNODES + NPB - 1) / NPB)  // 782

typedef __attribute__((ext_vector_type(8))) short bf16x8_t;  // 8 bf16 = 4 VGPR
typedef __attribute__((ext_vector_type(4))) float f32x4_t;

// ---------------------------------------------------------------------------
// CSR build: histogram -> scan -> bucketed two-pass scatter
// ---------------------------------------------------------------------------

__global__ __launch_bounds__(256) void hist_kernel(const int* __restrict__ dst,
                                                   int* __restrict__ counts) {
    int e = blockIdx.x * 256 + threadIdx.x;
    if (e < NEDGES) atomicAdd(&counts[dst[e]], 1);
}

__global__ __launch_bounds__(1024) void scan1_kernel(const int* __restrict__ counts,
                                                     int* __restrict__ row_ptr,
                                                     int* __restrict__ blk_sums) {
    __shared__ int s[1024];
    int t = threadIdx.x;
    int i = blockIdx.x * 1024 + t;
    int v = (i < NNODES) ? counts[i] : 0;
    s[t] = v;
    __syncthreads();
    for (int off = 1; off < 1024; off <<= 1) {
        int x = (t >= off) ? s[t - off] : 0;
        __syncthreads();
        s[t] += x;
        __syncthreads();
    }
    int incl = s[t];
    if (i < NNODES) row_ptr[i] = incl - v;  // exclusive (block-local)
    if (t == 1023) blk_sums[blockIdx.x] = incl;
}

__global__ void scan2_kernel(int* __restrict__ blk_sums, int nb) {
    if (threadIdx.x == 0 && blockIdx.x == 0) {
        int run = 0;
        for (int b = 0; b < nb; ++b) { int tv = blk_sums[b]; blk_sums[b] = run; run += tv; }
    }
}

__global__ __launch_bounds__(1024) void scan3_kernel(int* __restrict__ row_ptr,
                                                     const int* __restrict__ blk_sums) {
    int i = blockIdx.x * 1024 + threadIdx.x;
    if (i < NNODES) row_ptr[i] += blk_sums[blockIdx.x];
    if (i == 0) row_ptr[NNODES] = NEDGES;
}

__global__ __launch_bounds__(256) void init_bcur_kernel(const int* __restrict__ row_ptr,
                                                        int* __restrict__ bcur) {
    int b = blockIdx.x * 256 + threadIdx.x;
    if (b < NBUCKETS) bcur[b] = row_ptr[b * NPB];
}

// pass 1: bin edges by dst bucket; positions within bucket are arrival-order.
// src < 50000 < 2^16, so pack (local node id << 16 | src) into tmp.x.
__global__ __launch_bounds__(256) void bucket_kernel(const int* __restrict__ src,
                                                     const int* __restrict__ dst,
                                                     const float* __restrict__ w,
                                                     int* __restrict__ bcur,
                                                     int2* __restrict__ tmp) {
    int e = blockIdx.x * 256 + threadIdx.x;
    if (e < NEDGES) {
        int d = dst[e];
        int b = d >> 6;
        int p = atomicAdd(&bcur[b], 1);
        int2 v;
        v.x = ((d & 63) << 16) | src[e];
        v.y = __float_as_int(w[e]);
        tmp[p] = v;
    }
}

// pass 2: one block per bucket; sort bucket into final per-node CSR order via
// LDS cursors. All writes land inside the bucket's ~16 KB output window.
__global__ __launch_bounds__(256) void sort_kernel(const int* __restrict__ row_ptr,
                                                   const int2* __restrict__ tmp,
                                                   int2* __restrict__ edges) {
    __shared__ int lcur[NPB];
    int b = blockIdx.x;
    int t = threadIdx.x;
    int nb0 = b * NPB;
    if (t < NPB) {
        int node = nb0 + t;
        lcur[t] = (node < NNODES) ? row_ptr[node] : 0;
    }
    __syncthreads();
    int estart = row_ptr[nb0];
    int nend = nb0 + NPB;
    if (nend > NNODES) nend = NNODES;
    int eend = row_ptr[nend];
    for (int i = estart + t; i < eend; i += 256) {
        int2 v = tmp[i];
        int loc = v.x >> 16;
        int p = atomicAdd(&lcur[loc], 1);
        int2 o;
        o.x = v.x & 0xFFFF;
        o.y = v.y;
        edges[p] = o;
    }
}

// ---------------------------------------------------------------------------
// fp32 -> bf16 converts: x feature table; W0/Ws -> transposed bf16 W^T[n][k]
// ---------------------------------------------------------------------------

__global__ __launch_bounds__(256) void cvt_kernel(const float2* __restrict__ in,
                                                  __hip_bfloat162* __restrict__ out,
                                                  int n2) {
    int i = blockIdx.x * 256 + threadIdx.x;
    int stride = gridDim.x * 256;
    for (; i < n2; i += stride) {
        float2 v = in[i];
        __hip_bfloat162 b;
        b.x = __float2bfloat16(v.x);
        b.y = __float2bfloat16(v.y);
        out[i] = b;
    }
}

__global__ __launch_bounds__(256) void cvtw_kernel(const float* __restrict__ W0,
                                                   const float* __restrict__ Ws,
                                                   __hip_bfloat16* __restrict__ Wtb) {
    int idx = blockIdx.x * 256 + threadIdx.x;  // 0..65535 (4 matrices)
    int m = idx >> 14;
    int oi = idx & 16383;
    int n = oi >> 7;
    int k = oi & 127;
    const float* src = (m == 0) ? W0 : (Ws + (size_t)(m - 1) * NF * NF);
    Wtb[idx] = __float2bfloat16(src[k * NF + n]);
}

// ---------------------------------------------------------------------------
// SpMM: one wave per destination node, lane owns 2 features (bf16x2 gather,
// fp32 accumulate, bf16 output). agg[n][:] = sum_e w_e * feat[src_e][:]
// ---------------------------------------------------------------------------

__global__ __launch_bounds__(256) void spmm_kernel(const int* __restrict__ row_ptr,
                                                   const int2* __restrict__ edges,
                                                   const __hip_bfloat162* __restrict__ feat,
                                                   __hip_bfloat162* __restrict__ agg) {
    int wave = threadIdx.x >> 6;
    int lane = threadIdx.x & 63;
    int n = blockIdx.x * 4 + wave;

    int e0 = __builtin_amdgcn_readfirstlane(row_ptr[n]);
    int e1 = __builtin_amdgcn_readfirstlane(row_ptr[n + 1]);

    float ax = 0.f, ay = 0.f;

    int e = e0;
    for (; e + 3 < e1; e += 4) {
        int2 d0 = edges[e];
        int2 d1 = edges[e + 1];
        int2 d2 = edges[e + 2];
        int2 d3 = edges[e + 3];
        __hip_bfloat162 v0 = feat[(size_t)d0.x * 64 + lane];
        __hip_bfloat162 v1 = feat[(size_t)d1.x * 64 + lane];
        __hip_bfloat162 v2 = feat[(size_t)d2.x * 64 + lane];
        __hip_bfloat162 v3 = feat[(size_t)d3.x * 64 + lane];
        float w0 = __int_as_float(d0.y);
        float w1 = __int_as_float(d1.y);
        float w2 = __int_as_float(d2.y);
        float w3 = __int_as_float(d3.y);
        ax += w0 * __bfloat162float(v0.x) + w1 * __bfloat162float(v1.x);
        ay += w0 * __bfloat162float(v0.y) + w1 * __bfloat162float(v1.y);
        ax += w2 * __bfloat162float(v2.x) + w3 * __bfloat162float(v3.x);
        ay += w2 * __bfloat162float(v2.y) + w3 * __bfloat162float(v3.y);
    }
    for (; e < e1; ++e) {
        int2 d0 = edges[e];
        __hip_bfloat162 v0 = feat[(size_t)d0.x * 64 + lane];
        float w0 = __int_as_float(d0.y);
        ax += w0 * __bfloat162float(v0.x);
        ay += w0 * __bfloat162float(v0.y);
    }
    __hip_bfloat162 o;
    o.x = __float2bfloat16(ax);
    o.y = __float2bfloat16(ay);
    agg[(size_t)n * 64 + lane] = o;
}

// ---------------------------------------------------------------------------
// MFMA bf16 GEMM, no LDS: h[g][:] = relu(A[g][:] @ W + b) (+ h in-place res),
// optional bf16 table write. 256 threads = 4 waves; wave owns 16 rows x 128
// cols = 8 subtiles of 16x16, K = 128 = 4 k-steps of mfma_f32_16x16x32_bf16.
// A (bf16, row-major) and W^T (bf16, [n][k]) frag loads are 16 B/lane direct
// from global (A streamed once; W^T lives in L1/L2).
// C/D layout: col = lane&15, row = (lane>>4)*4 + reg   [m89-verified]
// ---------------------------------------------------------------------------

template <bool RES, bool WB16>
__global__ __launch_bounds__(256) void gemm_mfma_kernel(
    const __hip_bfloat16* __restrict__ A,
    const __hip_bfloat16* __restrict__ Wt,   // [n][k] bf16
    const float* __restrict__ bias,
    float* h,                                // out (in-out if RES)
    __hip_bfloat16* __restrict__ outb) {
    int t = threadIdx.x;
    int wave = t >> 6;
    int lane = t & 63;
    int lr = lane & 15;   // A-row / B-col / D-col within subtile
    int kg = lane >> 4;   // k-group (0..3)
    int row0 = blockIdx.x * 64 + wave * 16;

    int arow = row0 + lr;
    if (arow >= NNODES) arow = NNODES - 1;  // clamp; stores are guarded

    f32x4_t acc[8];
#pragma unroll
    for (int c = 0; c < 8; ++c) acc[c] = (f32x4_t){0.f, 0.f, 0.f, 0.f};

#pragma unroll
    for (int ks = 0; ks < 4; ++ks) {
        bf16x8_t af = *(const bf16x8_t*)&A[(size_t)arow * NF + ks * 32 + kg * 8];
#pragma unroll
        for (int c = 0; c < 8; ++c) {
            bf16x8_t bfr = *(const bf16x8_t*)&Wt[(size_t)(c * 16 + lr) * NF + ks * 32 + kg * 8];
            acc[c] = __builtin_amdgcn_mfma_f32_16x16x32_bf16(af, bfr, acc[c], 0, 0, 0);
        }
    }

    float bcol[8];
#pragma unroll
    for (int c = 0; c < 8; ++c) bcol[c] = bias[c * 16 + lr];

#pragma unroll
    for (int j = 0; j < 4; ++j) {
        int g = row0 + kg * 4 + j;
        if (g < NNODES) {
#pragma unroll
            for (int c = 0; c < 8; ++c) {
                int col = c * 16 + lr;
                float v = acc[c][j] + bcol[c];
                v = fmaxf(v, 0.f);
                if (RES) v += h[(size_t)g * NF + col];
                h[(size_t)g * NF + col] = v;
                if (WB16) outb[(size_t)g * NF + col] = __float2bfloat16(v);
            }
        }
    }
}

// ---------------------------------------------------------------------------
// Head GEMM: out[N,40] = h[N,128] @ Wout + bout (fp32, lW-only LDS)
// ---------------------------------------------------------------------------

__global__ __launch_bounds__(256) void head_kernel(const float* __restrict__ A,
                                                   const float* __restrict__ W,
                                                   const float* __restrict__ bias,
                                                   float* __restrict__ out) {
    __shared__ float lW[NF * NC];  // [k][j]
    int t = threadIdx.x;
    for (int idx = t * 4; idx < NF * NC; idx += 256 * 4) {
        *(float4*)&lW[idx] = *(const float4*)&W[idx];
    }
    __syncthreads();

    int m = t & 7;    // col group: cols m*5..m*5+4
    int rg = t >> 3;  // 0..31
    int row0 = blockIdx.x * 128 + rg * 4;

    float acc[4][5];
#pragma unroll
    for (int r = 0; r < 4; ++r)
#pragma unroll
        for (int j = 0; j < 5; ++j) acc[r][j] = 0.f;

    int gr[4];
#pragma unroll
    for (int r = 0; r < 4; ++r) {
        int g = row0 + r;
        gr[r] = g < NNODES ? g : NNODES - 1;
    }

    for (int k = 0; k < NF; k += 4) {
        float4 a4[4];
#pragma unroll
        for (int r = 0; r < 4; ++r)
            a4[r] = *(const float4*)&A[(size_t)gr[r] * NF + k];
#pragma unroll
        for (int kk = 0; kk < 4; ++kk) {
            float wv[5];
#pragma unroll
            for (int j = 0; j < 5; ++j) wv[j] = lW[(k + kk) * NC + m * 5 + j];
#pragma unroll
            for (int r = 0; r < 4; ++r) {
                float a = (kk == 0) ? a4[r].x : (kk == 1) ? a4[r].y : (kk == 2) ? a4[r].z : a4[r].w;
#pragma unroll
                for (int j = 0; j < 5; ++j) acc[r][j] += a * wv[j];
            }
        }
    }

#pragma unroll
    for (int r = 0; r < 4; ++r) {
        int g = row0 + r;
        if (g < NNODES) {
#pragma unroll
            for (int j = 0; j < 5; ++j) {
                out[(size_t)g * NC + m * 5 + j] = acc[r][j] + bias[m * 5 + j];
            }
        }
    }
}

// ---------------------------------------------------------------------------

extern "C" void kernel_launch(void* const* d_in, const int* in_sizes, int n_in,
                              void* d_out, int out_size, void* d_ws, size_t ws_size,
                              hipStream_t stream) {
    const float* x    = (const float*)d_in[0];
    const int*   esrc = (const int*)d_in[1];
    const int*   edst = (const int*)d_in[2];
    const float* ew   = (const float*)d_in[3];
    const float* W0   = (const float*)d_in[4];
    const float* b0   = (const float*)d_in[5];
    const float* Ws   = (const float*)d_in[6];
    const float* bs   = (const float*)d_in[7];
    const float* Wout = (const float*)d_in[8];
    const float* bout = (const float*)d_in[9];
    float* out = (float*)d_out;

    // workspace carve (256-B aligned); total ~65 MB
    char* p = (char*)d_ws;
    auto alloc = [&](size_t bytes) -> void* {
        void* r = (void*)p;
        p += (bytes + 255) & ~(size_t)255;
        return r;
    };
    int*   counts   = (int*)alloc((size_t)NNODES * 4);
    int*   row_ptr  = (int*)alloc((size_t)(NNODES + 1) * 4);
    int*   blk_sums = (int*)alloc(64 * 4);
    int*   bcur     = (int*)alloc((size_t)NBUCKETS * 4);
    int2*  tmp      = (int2*)alloc((size_t)NEDGES * 8);
    int2*  edges    = (int2*)alloc((size_t)NEDGES * 8);
    __hip_bfloat16* aggb = (__hip_bfloat16*)alloc((size_t)NNODES * NF * 2);
    float* h        = (float*)alloc((size_t)NNODES * NF * 4);
    __hip_bfloat16* hb   = (__hip_bfloat16*)alloc((size_t)NNODES * NF * 2);
    __hip_bfloat16* Wtb  = (__hip_bfloat16*)alloc((size_t)4 * NF * NF * 2);

    const int nb_scan = (NNODES + 1023) / 1024;   // 49
    const int gemm_grid = (NNODES + 63) / 64;     // 782
    const int head_grid = (NNODES + 127) / 128;   // 391

    // ---- CSR build (bucketed two-pass scatter) ----
    hipMemsetAsync(counts, 0, (size_t)NNODES * 4, stream);
    hist_kernel<<<NEDGES / 256, 256, 0, stream>>>(edst, counts);
    scan1_kernel<<<nb_scan, 1024, 0, stream>>>(counts, row_ptr, blk_sums);
    scan2_kernel<<<1, 64, 0, stream>>>(blk_sums, nb_scan);
    scan3_kernel<<<nb_scan, 1024, 0, stream>>>(row_ptr, blk_sums);
    init_bcur_kernel<<<(NBUCKETS + 255) / 256, 256, 0, stream>>>(row_ptr, bcur);
    bucket_kernel<<<NEDGES / 256, 256, 0, stream>>>(esrc, edst, ew, bcur, tmp);
    sort_kernel<<<NBUCKETS, 256, 0, stream>>>(row_ptr, tmp, edges);

    // ---- converts: x -> bf16 table; weights -> bf16 W^T ----
    cvt_kernel<<<2048, 256, 0, stream>>>((const float2*)x, (__hip_bfloat162*)hb, NNODES * 64);
    cvtw_kernel<<<256, 256, 0, stream>>>(W0, Ws, Wtb);

    // ---- layer 0: h = relu(spmm(xb) @ W0 + b0); emit bf16 copy ----
    spmm_kernel<<<NNODES / 4, 256, 0, stream>>>(row_ptr, edges, (const __hip_bfloat162*)hb,
                                                (__hip_bfloat162*)aggb);
    gemm_mfma_kernel<false, true>
        <<<gemm_grid, 256, 0, stream>>>(aggb, Wtb, b0, h, hb);

    // ---- residual layers (in-place residual on h) ----
    for (int l = 0; l < NLAYERS; ++l) {
        spmm_kernel<<<NNODES / 4, 256, 0, stream>>>(row_ptr, edges, (const __hip_bfloat162*)hb,
                                                    (__hip_bfloat162*)aggb);
        if (l < NLAYERS - 1) {
            gemm_mfma_kernel<true, true>
                <<<gemm_grid, 256, 0, stream>>>(aggb, Wtb + (size_t)(l + 1) * NF * NF,
                                                bs + (size_t)l * NF, h, hb);
        } else {
            gemm_mfma_kernel<true, false>
                <<<gemm_grid, 256, 0, stream>>>(aggb, Wtb + (size_t)(l + 1) * NF * NF,
                                                bs + (size_t)l * NF, h, nullptr);
        }
    }

    // ---- output head ----
    head_kernel<<<head_grid, 256, 0, stream>>>(h, Wout, bout, out);
}

// Round 4
// 460.809 us; speedup vs baseline: 1.9297x; 1.9297x over previous
//
#include <hip/hip_runtime.h>
#include <hip/hip_bf16.h>

#define NNODES 50000
#define NEDGES 1600000
#define NF 128
#define NC 40
#define NLAYERS 3
#define NPB 64                               // nodes per bucket
#define NBUCKETS ((NNODES + NPB - 1) / NPB)  // 782
#define NCHUNK 256                           // edge chunks (blocks) for counting sort
#define CE (NEDGES / NCHUNK)                 // 6250 edges per chunk
#define NSC (NBUCKETS * NCHUNK)              // 200192 count entries

typedef __attribute__((ext_vector_type(8))) short bf16x8_t;  // 8 bf16 = 4 VGPR
typedef __attribute__((ext_vector_type(4))) float f32x4_t;

// ---------------------------------------------------------------------------
// CSR build: deterministic counting sort by bucket (NO global atomics),
// then per-bucket node sort that also emits row_ptr.
// ---------------------------------------------------------------------------

// per-chunk bucket histogram -> counts[bucket][chunk]
__global__ __launch_bounds__(1024) void count_kernel(const int* __restrict__ dst,
                                                     int* __restrict__ counts) {
    __shared__ int hist[NBUCKETS];
    int t = threadIdx.x;
    for (int i = t; i < NBUCKETS; i += 1024) hist[i] = 0;
    __syncthreads();
    int e0 = blockIdx.x * CE;
    for (int e = e0 + t; e < e0 + CE; e += 1024) {
        atomicAdd(&hist[dst[e] >> 6], 1);
    }
    __syncthreads();
    for (int i = t; i < NBUCKETS; i += 1024) {
        counts[i * NCHUNK + blockIdx.x] = hist[i];
    }
}

// exclusive scan over NSC ints: scan1 (block-local) -> scan2 (block sums) -> scan3 (add)
__global__ __launch_bounds__(1024) void scan1_kernel(const int* __restrict__ in,
                                                     int* __restrict__ out,
                                                     int* __restrict__ blk_sums, int n) {
    __shared__ int s[1024];
    int t = threadIdx.x;
    int i = blockIdx.x * 1024 + t;
    int v = (i < n) ? in[i] : 0;
    s[t] = v;
    __syncthreads();
    for (int off = 1; off < 1024; off <<= 1) {
        int x = (t >= off) ? s[t - off] : 0;
        __syncthreads();
        s[t] += x;
        __syncthreads();
    }
    int incl = s[t];
    if (i < n) out[i] = incl - v;  // exclusive (block-local)
    if (t == 1023) blk_sums[blockIdx.x] = incl;
}

__global__ __launch_bounds__(256) void scan2_kernel(int* __restrict__ blk_sums, int nb) {
    __shared__ int s[256];
    int t = threadIdx.x;
    int v = (t < nb) ? blk_sums[t] : 0;
    s[t] = v;
    __syncthreads();
    for (int off = 1; off < 256; off <<= 1) {
        int x = (t >= off) ? s[t - off] : 0;
        __syncthreads();
        s[t] += x;
        __syncthreads();
    }
    if (t < nb) blk_sums[t] = s[t] - v;  // exclusive
}

__global__ __launch_bounds__(1024) void scan3_kernel(int* __restrict__ out,
                                                     const int* __restrict__ blk_sums, int n) {
    int i = blockIdx.x * 1024 + threadIdx.x;
    if (i < n) out[i] += blk_sums[blockIdx.x];
}

// re-read edges; place into bucket-sorted tmp via LDS cursors (exact positions
// precomputed by the scan -> no global atomics, writes are ~8-edge runs/bucket).
__global__ __launch_bounds__(1024) void scatter2_kernel(const int* __restrict__ src,
                                                        const int* __restrict__ dst,
                                                        const float* __restrict__ w,
                                                        const int* __restrict__ scanned,
                                                        int2* __restrict__ tmp) {
    __shared__ int cur[NBUCKETS];
    int t = threadIdx.x;
    for (int i = t; i < NBUCKETS; i += 1024) {
        cur[i] = scanned[i * NCHUNK + blockIdx.x];
    }
    __syncthreads();
    int e0 = blockIdx.x * CE;
    for (int e = e0 + t; e < e0 + CE; e += 1024) {
        int d = dst[e];
        int p = atomicAdd(&cur[d >> 6], 1);  // LDS atomic
        int2 v;
        v.x = ((d & 63) << 16) | src[e];
        v.y = __float_as_int(w[e]);
        tmp[p] = v;
    }
}

// one block per bucket: node-level histogram + scan in LDS -> final CSR order;
// also writes row_ptr for the bucket's 64 nodes.
__global__ __launch_bounds__(256) void sort2_kernel(const int* __restrict__ scanned,
                                                    const int2* __restrict__ tmp,
                                                    int2* __restrict__ edges,
                                                    int* __restrict__ row_ptr) {
    __shared__ int hist[NPB];
    __shared__ int cur[NPB];
    int b = blockIdx.x;
    int t = threadIdx.x;
    int estart = scanned[b * NCHUNK];
    int eend = (b == NBUCKETS - 1) ? NEDGES : scanned[(b + 1) * NCHUNK];

    if (t < NPB) hist[t] = 0;
    __syncthreads();
    for (int e = estart + t; e < eend; e += 256) {
        atomicAdd(&hist[tmp[e].x >> 16], 1);  // LDS atomic
    }
    __syncthreads();
    if (t == 0) {
        int run = estart;
#pragma unroll
        for (int i = 0; i < NPB; ++i) {
            int c = hist[i];
            hist[i] = run;  // exclusive start
            run += c;
        }
    }
    __syncthreads();
    int nb0 = b * NPB;
    if (t < NPB) {
        int node = nb0 + t;
        if (node < NNODES) row_ptr[node] = hist[t];
        cur[t] = hist[t];
    }
    if (b == NBUCKETS - 1 && t == 0) row_ptr[NNODES] = NEDGES;
    __syncthreads();
    for (int e = estart + t; e < eend; e += 256) {
        int2 v = tmp[e];
        int loc = v.x >> 16;
        int p = atomicAdd(&cur[loc], 1);  // LDS atomic
        int2 o;
        o.x = v.x & 0xFFFF;
        o.y = v.y;
        edges[p] = o;
    }
}

// ---------------------------------------------------------------------------
// fp32 -> bf16 converts: x feature table; W0/Ws -> transposed bf16 W^T[n][k]
// ---------------------------------------------------------------------------

__global__ __launch_bounds__(256) void cvt_kernel(const float2* __restrict__ in,
                                                  __hip_bfloat162* __restrict__ out,
                                                  int n2) {
    int i = blockIdx.x * 256 + threadIdx.x;
    int stride = gridDim.x * 256;
    for (; i < n2; i += stride) {
        float2 v = in[i];
        __hip_bfloat162 b;
        b.x = __float2bfloat16(v.x);
        b.y = __float2bfloat16(v.y);
        out[i] = b;
    }
}

__global__ __launch_bounds__(256) void cvtw_kernel(const float* __restrict__ W0,
                                                   const float* __restrict__ Ws,
                                                   __hip_bfloat16* __restrict__ Wtb) {
    int idx = blockIdx.x * 256 + threadIdx.x;  // 0..65535 (4 matrices)
    int m = idx >> 14;
    int oi = idx & 16383;
    int n = oi >> 7;
    int k = oi & 127;
    const float* src = (m == 0) ? W0 : (Ws + (size_t)(m - 1) * NF * NF);
    Wtb[idx] = __float2bfloat16(src[k * NF + n]);
}

// ---------------------------------------------------------------------------
// SpMM: one wave per destination node, lane owns 2 features (bf16x2 gather,
// fp32 accumulate, bf16 output). agg[n][:] = sum_e w_e * feat[src_e][:]
// ---------------------------------------------------------------------------

__global__ __launch_bounds__(256) void spmm_kernel(const int* __restrict__ row_ptr,
                                                   const int2* __restrict__ edges,
                                                   const __hip_bfloat162* __restrict__ feat,
                                                   __hip_bfloat162* __restrict__ agg) {
    int wave = threadIdx.x >> 6;
    int lane = threadIdx.x & 63;
    int n = blockIdx.x * 4 + wave;

    int e0 = __builtin_amdgcn_readfirstlane(row_ptr[n]);
    int e1 = __builtin_amdgcn_readfirstlane(row_ptr[n + 1]);

    float ax = 0.f, ay = 0.f;

    int e = e0;
    for (; e + 3 < e1; e += 4) {
        int2 d0 = edges[e];
        int2 d1 = edges[e + 1];
        int2 d2 = edges[e + 2];
        int2 d3 = edges[e + 3];
        __hip_bfloat162 v0 = feat[(size_t)d0.x * 64 + lane];
        __hip_bfloat162 v1 = feat[(size_t)d1.x * 64 + lane];
        __hip_bfloat162 v2 = feat[(size_t)d2.x * 64 + lane];
        __hip_bfloat162 v3 = feat[(size_t)d3.x * 64 + lane];
        float w0 = __int_as_float(d0.y);
        float w1 = __int_as_float(d1.y);
        float w2 = __int_as_float(d2.y);
        float w3 = __int_as_float(d3.y);
        ax += w0 * __bfloat162float(v0.x) + w1 * __bfloat162float(v1.x);
        ay += w0 * __bfloat162float(v0.y) + w1 * __bfloat162float(v1.y);
        ax += w2 * __bfloat162float(v2.x) + w3 * __bfloat162float(v3.x);
        ay += w2 * __bfloat162float(v2.y) + w3 * __bfloat162float(v3.y);
    }
    for (; e < e1; ++e) {
        int2 d0 = edges[e];
        __hip_bfloat162 v0 = feat[(size_t)d0.x * 64 + lane];
        float w0 = __int_as_float(d0.y);
        ax += w0 * __bfloat162float(v0.x);
        ay += w0 * __bfloat162float(v0.y);
    }
    __hip_bfloat162 o;
    o.x = __float2bfloat16(ax);
    o.y = __float2bfloat16(ay);
    agg[(size_t)n * 64 + lane] = o;
}

// ---------------------------------------------------------------------------
// MFMA bf16 GEMM, no LDS: h[g][:] = relu(A[g][:] @ W + b) (+ h in-place res),
// optional bf16 table write. 256 threads = 4 waves; wave owns 16 rows x 128
// cols = 8 subtiles of 16x16, K = 128 = 4 k-steps of mfma_f32_16x16x32_bf16.
// C/D layout: col = lane&15, row = (lane>>4)*4 + reg   [m89-verified]
// ---------------------------------------------------------------------------

template <bool RES, bool WB16>
__global__ __launch_bounds__(256) void gemm_mfma_kernel(
    const __hip_bfloat16* __restrict__ A,
    const __hip_bfloat16* __restrict__ Wt,   // [n][k] bf16
    const float* __restrict__ bias,
    float* h,                                // out (in-out if RES)
    __hip_bfloat16* __restrict__ outb) {
    int t = threadIdx.x;
    int wave = t >> 6;
    int lane = t & 63;
    int lr = lane & 15;   // A-row / B-col / D-col within subtile
    int kg = lane >> 4;   // k-group (0..3)
    int row0 = blockIdx.x * 64 + wave * 16;

    int arow = row0 + lr;
    if (arow >= NNODES) arow = NNODES - 1;  // clamp; stores are guarded

    f32x4_t acc[8];
#pragma unroll
    for (int c = 0; c < 8; ++c) acc[c] = (f32x4_t){0.f, 0.f, 0.f, 0.f};

#pragma unroll
    for (int ks = 0; ks < 4; ++ks) {
        bf16x8_t af = *(const bf16x8_t*)&A[(size_t)arow * NF + ks * 32 + kg * 8];
#pragma unroll
        for (int c = 0; c < 8; ++c) {
            bf16x8_t bfr = *(const bf16x8_t*)&Wt[(size_t)(c * 16 + lr) * NF + ks * 32 + kg * 8];
            acc[c] = __builtin_amdgcn_mfma_f32_16x16x32_bf16(af, bfr, acc[c], 0, 0, 0);
        }
    }

    float bcol[8];
#pragma unroll
    for (int c = 0; c < 8; ++c) bcol[c] = bias[c * 16 + lr];

#pragma unroll
    for (int j = 0; j < 4; ++j) {
        int g = row0 + kg * 4 + j;
        if (g < NNODES) {
#pragma unroll
            for (int c = 0; c < 8; ++c) {
                int col = c * 16 + lr;
                float v = acc[c][j] + bcol[c];
                v = fmaxf(v, 0.f);
                if (RES) v += h[(size_t)g * NF + col];
                h[(size_t)g * NF + col] = v;
                if (WB16) outb[(size_t)g * NF + col] = __float2bfloat16(v);
            }
        }
    }
}

// ---------------------------------------------------------------------------
// Head GEMM: out[N,40] = h[N,128] @ Wout + bout (fp32, lW-only LDS)
// ---------------------------------------------------------------------------

__global__ __launch_bounds__(256) void head_kernel(const float* __restrict__ A,
                                                   const float* __restrict__ W,
                                                   const float* __restrict__ bias,
                                                   float* __restrict__ out) {
    __shared__ float lW[NF * NC];  // [k][j]
    int t = threadIdx.x;
    for (int idx = t * 4; idx < NF * NC; idx += 256 * 4) {
        *(float4*)&lW[idx] = *(const float4*)&W[idx];
    }
    __syncthreads();

    int m = t & 7;    // col group: cols m*5..m*5+4
    int rg = t >> 3;  // 0..31
    int row0 = blockIdx.x * 128 + rg * 4;

    float acc[4][5];
#pragma unroll
    for (int r = 0; r < 4; ++r)
#pragma unroll
        for (int j = 0; j < 5; ++j) acc[r][j] = 0.f;

    int gr[4];
#pragma unroll
    for (int r = 0; r < 4; ++r) {
        int g = row0 + r;
        gr[r] = g < NNODES ? g : NNODES - 1;
    }

    for (int k = 0; k < NF; k += 4) {
        float4 a4[4];
#pragma unroll
        for (int r = 0; r < 4; ++r)
            a4[r] = *(const float4*)&A[(size_t)gr[r] * NF + k];
#pragma unroll
        for (int kk = 0; kk < 4; ++kk) {
            float wv[5];
#pragma unroll
            for (int j = 0; j < 5; ++j) wv[j] = lW[(k + kk) * NC + m * 5 + j];
#pragma unroll
            for (int r = 0; r < 4; ++r) {
                float a = (kk == 0) ? a4[r].x : (kk == 1) ? a4[r].y : (kk == 2) ? a4[r].z : a4[r].w;
#pragma unroll
                for (int j = 0; j < 5; ++j) acc[r][j] += a * wv[j];
            }
        }
    }

#pragma unroll
    for (int r = 0; r < 4; ++r) {
        int g = row0 + r;
        if (g < NNODES) {
#pragma unroll
            for (int j = 0; j < 5; ++j) {
                out[(size_t)g * NC + m * 5 + j] = acc[r][j] + bias[m * 5 + j];
            }
        }
    }
}

// ---------------------------------------------------------------------------

extern "C" void kernel_launch(void* const* d_in, const int* in_sizes, int n_in,
                              void* d_out, int out_size, void* d_ws, size_t ws_size,
                              hipStream_t stream) {
    const float* x    = (const float*)d_in[0];
    const int*   esrc = (const int*)d_in[1];
    const int*   edst = (const int*)d_in[2];
    const float* ew   = (const float*)d_in[3];
    const float* W0   = (const float*)d_in[4];
    const float* b0   = (const float*)d_in[5];
    const float* Ws   = (const float*)d_in[6];
    const float* bs   = (const float*)d_in[7];
    const float* Wout = (const float*)d_in[8];
    const float* bout = (const float*)d_in[9];
    float* out = (float*)d_out;

    // workspace carve (256-B aligned); total ~79 MB
    char* p = (char*)d_ws;
    auto alloc = [&](size_t bytes) -> void* {
        void* r = (void*)p;
        p += (bytes + 255) & ~(size_t)255;
        return r;
    };
    int*   row_ptr  = (int*)alloc((size_t)(NNODES + 1) * 4);
    int*   counts   = (int*)alloc((size_t)NSC * 4);
    int*   scanned  = (int*)alloc((size_t)NSC * 4);
    int*   blk_sums = (int*)alloc(256 * 4);
    int2*  tmp      = (int2*)alloc((size_t)NEDGES * 8);
    int2*  edges    = (int2*)alloc((size_t)NEDGES * 8);
    __hip_bfloat16* aggb = (__hip_bfloat16*)alloc((size_t)NNODES * NF * 2);
    float* h        = (float*)alloc((size_t)NNODES * NF * 4);
    __hip_bfloat16* hb   = (__hip_bfloat16*)alloc((size_t)NNODES * NF * 2);
    __hip_bfloat16* Wtb  = (__hip_bfloat16*)alloc((size_t)4 * NF * NF * 2);

    const int nb_sc = (NSC + 1023) / 1024;        // 196
    const int gemm_grid = (NNODES + 63) / 64;     // 782
    const int head_grid = (NNODES + 127) / 128;   // 391

    // ---- CSR build: counting sort by bucket, then per-bucket node sort ----
    count_kernel<<<NCHUNK, 1024, 0, stream>>>(edst, counts);
    scan1_kernel<<<nb_sc, 1024, 0, stream>>>(counts, scanned, blk_sums, NSC);
    scan2_kernel<<<1, 256, 0, stream>>>(blk_sums, nb_sc);
    scan3_kernel<<<nb_sc, 1024, 0, stream>>>(scanned, blk_sums, NSC);
    scatter2_kernel<<<NCHUNK, 1024, 0, stream>>>(esrc, edst, ew, scanned, tmp);
    sort2_kernel<<<NBUCKETS, 256, 0, stream>>>(scanned, tmp, edges, row_ptr);

    // ---- converts: x -> bf16 table; weights -> bf16 W^T ----
    cvt_kernel<<<2048, 256, 0, stream>>>((const float2*)x, (__hip_bfloat162*)hb, NNODES * 64);
    cvtw_kernel<<<256, 256, 0, stream>>>(W0, Ws, Wtb);

    // ---- layer 0: h = relu(spmm(xb) @ W0 + b0); emit bf16 copy ----
    spmm_kernel<<<NNODES / 4, 256, 0, stream>>>(row_ptr, edges, (const __hip_bfloat162*)hb,
                                                (__hip_bfloat162*)aggb);
    gemm_mfma_kernel<false, true>
        <<<gemm_grid, 256, 0, stream>>>(aggb, Wtb, b0, h, hb);

    // ---- residual layers (in-place residual on h) ----
    for (int l = 0; l < NLAYERS; ++l) {
        spmm_kernel<<<NNODES / 4, 256, 0, stream>>>(row_ptr, edges, (const __hip_bfloat162*)hb,
                                                    (__hip_bfloat162*)aggb);
        if (l < NLAYERS - 1) {
            gemm_mfma_kernel<true, true>
                <<<gemm_grid, 256, 0, stream>>>(aggb, Wtb + (size_t)(l + 1) * NF * NF,
                                                bs + (size_t)l * NF, h, hb);
        } else {
            gemm_mfma_kernel<true, false>
                <<<gemm_grid, 256, 0, stream>>>(aggb, Wtb + (size_t)(l + 1) * NF * NF,
                                                bs + (size_t)l * NF, h, nullptr);
        }
    }

    // ---- output head ----
    head_kernel<<<head_grid, 256, 0, stream>>>(h, Wout, bout, out);
}